// Round 8
// baseline (85.808 us; speedup 1.0000x reference)
//
#include <hip/hip_runtime.h>

#define T_TOTAL 262144
#define NBLOCKS 1024
#define NMIX 64
#define NDIM 16

typedef short bf16x8 __attribute__((ext_vector_type(8)));
typedef unsigned short u16x8 __attribute__((ext_vector_type(8)));
typedef unsigned short u16x4 __attribute__((ext_vector_type(4)));
typedef float f32x4 __attribute__((ext_vector_type(4)));

__device__ __forceinline__ unsigned short f2bf(float f) {
    union { float f; unsigned u; } v; v.f = f;
    unsigned r = v.u + 0x7fff + ((v.u >> 16) & 1);   // RNE
    return (unsigned short)(r >> 16);
}
__device__ __forceinline__ float bf2f(unsigned short s) {
    union { unsigned u; float f; } v; v.u = ((unsigned)s) << 16;
    return v.f;
}

// LDS layout (bytes) — total 22080 (no F staging; A-frags come from global):
//   L_WH  0      64 rows x 80 B (32 bf16 + pad)     5120
//   L_WL  5120                                       5120
//   L_MUT 10240  16 rows x 144 B (64 bf16 + pad)     2304
//   L_A2  12544  64 f32                               256
//   L_RED 12800  4 f32 loglike partials                64
//   L_P   12864  4 waves x 16 rows x 144 B           9216
#define L_WH   0
#define L_WL   5120
#define L_MUT  10240
#define L_A2   12544
#define L_RED  12800
#define L_P    12864

__global__ __launch_bounds__(256, 4) void gmm_main(const float* __restrict__ data,
                                                   const float* __restrict__ wghts,
                                                   const float* __restrict__ means,
                                                   const float* __restrict__ dcovs,
                                                   float* __restrict__ out,
                                                   float* __restrict__ part) {
    __shared__ __align__(16) char lds[22080];
    const int tid  = threadIdx.x;
    const int w    = tid >> 6;        // wave id
    const int lane = tid & 63;
    const int gi   = lane & 15;       // fragment row/col index
    const int gq   = lane >> 4;       // fragment quad
    const size_t tblk = (size_t)blockIdx.x * 256;   // 256 points/block, 64/wave

    // ---- phase A: issue ALL data loads up front (overlap with W prep).
    //      Lane (gi,gq) needs dims [(gq&1)*8 .. +8) of point w*64+rt*16+gi;
    //      gq>=2 lanes duplicate gq<2 addresses (L1 hit, HBM once). ----
    float4 xva[4], xvb[4];
    {
        const float* base = data + (tblk + w * 64 + gi) * 16 + (gq & 1) * 8;
#pragma unroll
        for (int rt = 0; rt < 4; ++rt) {
            const float4* xp = (const float4*)(base + rt * 16 * 16);
            xva[rt] = xp[0];
            xvb[rt] = xp[1];
        }
    }

    // ---- phase B: distributed W/MU/A2 prep: 4 threads per mixture ----
    {
        const int m  = tid >> 2;
        const int ql = tid & 3;       // dim-quarter
        const float LOG2E = 1.4426950408889634f;
        const float LOG2_2PI = 2.6514961294723187f;  // log2(6.283185307)
        const float4 d4 = *(const float4*)(dcovs + m * 16 + ql * 4);
        const float4 m4 = *(const float4*)(means + m * 16 + ql * 4);
        const float wm = wghts[m];
        float dc[4] = {d4.x, d4.y, d4.z, d4.w};
        float mu[4] = {m4.x, m4.y, m4.z, m4.w};
        u16x4 ghv, glv, hhv, hlv;
        float sumlog = 0.0f, qsum = 0.0f;
        unsigned short* mut = (unsigned short*)(lds + L_MUT);
#pragma unroll
        for (int j = 0; j < 4; ++j) {
            float pr = __builtin_amdgcn_rcpf(dc[j]);
            float g = -0.5f * LOG2E * pr;     // coeff of x^2
            float h = LOG2E * pr * mu[j];     // coeff of x
            unsigned short gH = f2bf(g), hH = f2bf(h);
            ghv[j] = gH;  glv[j] = f2bf(g - bf2f(gH));
            hhv[j] = hH;  hlv[j] = f2bf(h - bf2f(hH));
            mut[(ql * 4 + j) * 72 + m] = f2bf(mu[j]);
            sumlog += __builtin_amdgcn_logf(dc[j]);   // log2
            qsum   += pr * mu[j] * mu[j];
        }
        char* wrh = lds + L_WH + m * 80;
        char* wrl = lds + L_WL + m * 80;
        *(u16x4*)(wrh + ql * 8)      = ghv;
        *(u16x4*)(wrh + 32 + ql * 8) = hhv;
        *(u16x4*)(wrl + ql * 8)      = glv;
        *(u16x4*)(wrl + 32 + ql * 8) = hlv;
        sumlog += __shfl_xor(sumlog, 1); sumlog += __shfl_xor(sumlog, 2);
        qsum   += __shfl_xor(qsum, 1);   qsum   += __shfl_xor(qsum, 2);
        if (ql == 0) {
            float log2C = __builtin_amdgcn_logf(wm) - 8.0f * LOG2_2PI - 0.5f * sumlog;
            ((float*)(lds + L_A2))[m] = log2C - 0.5f * LOG2E * qsum;
        }
    }
    __syncthreads();

    // ---- preload B fragments (wave-invariant) ----
    bf16x8 bh[4], bl[4];
    float a2v[4];
#pragma unroll
    for (int c = 0; c < 4; ++c) {
        bh[c] = *(const bf16x8*)(lds + L_WH + (c * 16 + gi) * 80 + gq * 16);
        bl[c] = *(const bf16x8*)(lds + L_WL + (c * 16 + gi) * 80 + gq * 16);
        a2v[c] = ((const float*)(lds + L_A2))[c * 16 + gi];
    }
    bf16x8 mf0 = *(const bf16x8*)(lds + L_MUT + gi * 144 + gq * 16);
    bf16x8 mf1 = *(const bf16x8*)(lds + L_MUT + gi * 144 + 64 + gq * 16);

    char* pbase = lds + L_P + w * 2304;
    float ll_acc = 0.0f;
    const bool sq = (gq < 2);   // this lane's k-range holds x^2 terms

#pragma unroll
    for (int rt = 0; rt < 4; ++rt) {
        // A-fragment in registers: square (gq<2) and hi/lo bf16 split
        float4 a4 = xva[rt], b4 = xvb[rt];
        float xv[8] = {a4.x, a4.y, a4.z, a4.w, b4.x, b4.y, b4.z, b4.w};
        u16x8 ahv, alv;
#pragma unroll
        for (int d = 0; d < 8; ++d) {
            float v = sq ? xv[d] * xv[d] : xv[d];
            unsigned short vh = f2bf(v);
            ahv[d] = vh;
            alv[d] = f2bf(v - bf2f(vh));
        }
        bf16x8 ah = (bf16x8)ahv, al = (bf16x8)alv;

        // S = fl*wh + fh*wl + fh*wh  (hi/lo split), 4 column tiles of 16 m
        f32x4 pacc[4];
#pragma unroll
        for (int c = 0; c < 4; ++c) {
            f32x4 a = {0.0f, 0.0f, 0.0f, 0.0f};
            a = __builtin_amdgcn_mfma_f32_16x16x32_bf16(al, bh[c], a, 0, 0, 0);
            a = __builtin_amdgcn_mfma_f32_16x16x32_bf16(ah, bl[c], a, 0, 0, 0);
            a = __builtin_amdgcn_mfma_f32_16x16x32_bf16(ah, bh[c], a, 0, 0, 0);
            pacc[c] = a;
        }

        // exp2 + row sums (C layout: row = gq*4+reg, col = c*16+gi)
        float p[4][4], prow[4], inv[4];
#pragma unroll
        for (int reg = 0; reg < 4; ++reg) {
#pragma unroll
            for (int c = 0; c < 4; ++c)
                p[c][reg] = __builtin_amdgcn_exp2f(pacc[c][reg] + a2v[c]);
            prow[reg] = (p[0][reg] + p[1][reg]) + (p[2][reg] + p[3][reg]);
        }
#pragma unroll
        for (int reg = 0; reg < 4; ++reg) {
            float v = prow[reg];
            v += __shfl_xor(v, 1);  v += __shfl_xor(v, 2);
            v += __shfl_xor(v, 4);  v += __shfl_xor(v, 8);
            v = fmaxf(v, 1e-35f);
            ll_acc += __builtin_amdgcn_logf(v);       // log2
            inv[reg] = __builtin_amdgcn_rcpf(v);
        }

        // P -> bf16, C layout -> A layout via wave-local LDS tile
#pragma unroll
        for (int c = 0; c < 4; ++c)
#pragma unroll
            for (int reg = 0; reg < 4; ++reg)
                *(unsigned short*)(pbase + (gq * 4 + reg) * 144 + (c * 16 + gi) * 2) =
                    f2bf(p[c][reg]);

        // E = P @ MU  (K=64, 2 k-steps)
        bf16x8 ap0 = *(const bf16x8*)(pbase + gi * 144 + gq * 16);
        bf16x8 ap1 = *(const bf16x8*)(pbase + gi * 144 + 64 + gq * 16);
        f32x4 e = {0.0f, 0.0f, 0.0f, 0.0f};
        e = __builtin_amdgcn_mfma_f32_16x16x32_bf16(ap0, mf0, e, 0, 0, 0);
        e = __builtin_amdgcn_mfma_f32_16x16x32_bf16(ap1, mf1, e, 0, 0, 0);

        size_t trow = tblk + (size_t)w * 64 + rt * 16 + gq * 4;
#pragma unroll
        for (int reg = 0; reg < 4; ++reg)
            out[1 + (trow + reg) * 16 + gi] = e[reg] * inv[reg];
    }

    // ---- per-block loglike partial: plain store to distinct address.
    //      (single-address atomics serialize ~20ns/RMW [R6]; agent-scope
    //       fences flush L2 per block [R5]; kernel-boundary WB-INV makes
    //       these stores visible to gmm_fin.) ----
    ll_acc += __shfl_xor(ll_acc, 16);
    ll_acc += __shfl_xor(ll_acc, 32);
    if (lane == 0) ((float*)(lds + L_RED))[w] = ll_acc;
    __syncthreads();
    if (tid == 0) {
        float* r = (float*)(lds + L_RED);
        part[blockIdx.x] = (r[0] + r[1]) + (r[2] + r[3]);
    }
}

__global__ void gmm_fin(const float* __restrict__ part, float* __restrict__ out) {
    __shared__ double red[4];
    const int tid = threadIdx.x;
    double s = 0.0;
#pragma unroll
    for (int k = 0; k < 4; ++k) s += (double)part[tid + k * 256];
#pragma unroll
    for (int off = 32; off > 0; off >>= 1) s += __shfl_down(s, off, 64);
    const int wv = tid >> 6, lane = tid & 63;
    if (lane == 0) red[wv] = s;
    __syncthreads();
    if (tid == 0) {
        const double LN2 = 0.6931471805599453;
        double tot = (red[0] + red[1]) + (red[2] + red[3]);
        out[0] = (float)(tot * LN2 / (double)T_TOTAL);
    }
}

extern "C" void kernel_launch(void* const* d_in, const int* in_sizes, int n_in,
                              void* d_out, int out_size, void* d_ws, size_t ws_size,
                              hipStream_t stream) {
    const float* data  = (const float*)d_in[0];
    const float* wghts = (const float*)d_in[1];
    const float* means = (const float*)d_in[2];
    const float* dcovs = (const float*)d_in[3];
    float* out  = (float*)d_out;
    float* part = (float*)d_ws;   // 1024 fp32 partials (distinct addresses)

    gmm_main<<<NBLOCKS, 256, 0, stream>>>(data, wghts, means, dcovs, out, part);
    gmm_fin<<<1, 256, 0, stream>>>(part, out);
}